// Round 1
// baseline (179.328 us; speedup 1.0000x reference)
//
#include <hip/hip_runtime.h>

typedef __attribute__((ext_vector_type(8))) short short8;
typedef __attribute__((ext_vector_type(4))) float f32x4;

#define M_   512
#define N_   4096
#define D_   128
#define P_   3584
#define NKV  1024
#define L_   4096
#define H_   32

__device__ __forceinline__ ushort f2bf(float f) {
  union { float f; unsigned u; } v; v.f = f;
  unsigned r = (v.u + 0x7fffu + ((v.u >> 16) & 1u)) >> 16;
  return (ushort)r;
}
__device__ __forceinline__ float bf2f(ushort u) {
  union { unsigned u; float f; } v; v.u = ((unsigned)u) << 16;
  return v.f;
}

__device__ __forceinline__ void gload_lds16(const void* g, void* l) {
  __builtin_amdgcn_global_load_lds(
      (const __attribute__((address_space(1))) void*)g,
      (__attribute__((address_space(3))) void*)l, 16, 0, 0);
}

// ---------------------------------------------------------------------------
// Kernel A: X fp32 -> bf16, pre-swizzled chunk layout.
// ---------------------------------------------------------------------------
__global__ __launch_bounds__(256) void xconv(const float* __restrict__ X,
                                             ushort* __restrict__ Xs)
{
  int g = blockIdx.x * 256 + threadIdx.x;
  int row = g >> 9;
  int cir = g & 511;
  int grp = cir >> 3, ch = cir & 7;
  const float* src = &X[(size_t)row * 4096 + cir * 8];
  float4 f0 = *reinterpret_cast<const float4*>(src);
  float4 f1 = *reinterpret_cast<const float4*>(src + 4);
  short8 s;
  s[0] = f2bf(f0.x); s[1] = f2bf(f0.y); s[2] = f2bf(f0.z); s[3] = f2bf(f0.w);
  s[4] = f2bf(f1.x); s[5] = f2bf(f1.y); s[6] = f2bf(f1.z); s[7] = f2bf(f1.w);
  int dcol = grp * 64 + ((ch ^ (row & 7)) * 8);
  *reinterpret_cast<short8*>(&Xs[(size_t)row * 4096 + dcol]) = s;
}

// ---------------------------------------------------------------------------
// Kernel B: transpose+convert W -> Wt[6144][4096] bf16, pre-swizzled.
// ---------------------------------------------------------------------------
__global__ __launch_bounds__(256) void wtrans(
    const float* __restrict__ Wq, const float* __restrict__ Wk,
    const float* __restrict__ Wv, ushort* __restrict__ Wt)
{
  int bx = blockIdx.x;
  int by = blockIdx.y;
  const float* W; int wcols, c0;
  if (by < 64)      { W = Wq; wcols = 4096; c0 = by * 64; }
  else if (by < 80) { W = Wk; wcols = 1024; c0 = (by - 64) * 64; }
  else              { W = Wv; wcols = 1024; c0 = (by - 80) * 64; }
  int orow0 = by * 64;
  int r0 = bx * 64;
  __shared__ float T[64][65];
  int tid = threadIdx.x;

  #pragma unroll
  for (int i = 0; i < 4; ++i) {
    int r = i * 16 + (tid >> 4);
    int c4 = tid & 15;
    float4 f = *reinterpret_cast<const float4*>(&W[(size_t)(r0 + r) * wcols + c0 + c4 * 4]);
    T[r][c4 * 4 + 0] = f.x; T[r][c4 * 4 + 1] = f.y;
    T[r][c4 * 4 + 2] = f.z; T[r][c4 * 4 + 3] = f.w;
  }
  __syncthreads();

  #pragma unroll
  for (int i = 0; i < 2; ++i) {
    int j = i * 256 + tid;
    int orr = j >> 3;
    int ch = j & 7;
    short8 s;
    #pragma unroll
    for (int e = 0; e < 8; ++e) s[e] = f2bf(T[ch * 8 + e][orr]);
    int orow = orow0 + orr;
    int dstch = ch ^ (orow & 7);
    *reinterpret_cast<short8*>(&Wt[(size_t)orow * 4096 + r0 + dstch * 8]) = s;
  }
}

// ---------------------------------------------------------------------------
// Kernel C: K-split GEMM. pg[split][512][6144] = Xs @ Wt^T over K-half.
// ---------------------------------------------------------------------------
#define GEMM_STAGE(buf, k0g) do {                                             \
    _Pragma("unroll")                                                         \
    for (int i_ = 0; i_ < 4; ++i_) {                                          \
      int blk_ = w * 4 + i_;                                                  \
      gload_lds16(Asrc + (size_t)(blk_ * 8 + (lane >> 3)) * 4096 + (k0g) + (lane & 7) * 8, \
                  &As[buf][blk_ * 512]);                                      \
    }                                                                         \
    _Pragma("unroll")                                                         \
    for (int i_ = 0; i_ < 4; ++i_) {                                          \
      int blk_ = w * 4 + i_;                                                  \
      gload_lds16(Bsrc + (size_t)(blk_ * 8 + (lane >> 3)) * 4096 + (k0g) + (lane & 7) * 8, \
                  &Bs[buf][blk_ * 512]);                                      \
    }                                                                         \
  } while (0)

__global__ __launch_bounds__(256, 2) void qkv_gemm3(
    const ushort* __restrict__ Xs, const ushort* __restrict__ Wt,
    float* __restrict__ pg)
{
  const int bx = blockIdx.x;
  const int by = blockIdx.y;
  const int bz = blockIdx.z;
  const int tid = threadIdx.x, lane = tid & 63, w = tid >> 6;
  const int wr = w >> 1, wc = w & 1;
  const int m0 = by * 128, n0 = bx * 128;
  const int kb0 = bz * 2048;

  __shared__ ushort As[2][128 * 64];
  __shared__ ushort Bs[2][128 * 64];

  f32x4 acc[4][4];
  #pragma unroll
  for (int m = 0; m < 4; ++m)
    #pragma unroll
    for (int n = 0; n < 4; ++n)
      acc[m][n] = (f32x4){0.f, 0.f, 0.f, 0.f};

  const ushort* Asrc = Xs + (size_t)m0 * 4096;
  const ushort* Bsrc = Wt + (size_t)n0 * 4096;

  GEMM_STAGE(0, kb0);
  __syncthreads();
  int cur = 0;

  for (int kt = 0; kt < 32; ++kt) {
    if (kt + 1 < 32) GEMM_STAGE(cur ^ 1, kb0 + (kt + 1) * 64);
    #pragma unroll
    for (int kk = 0; kk < 2; ++kk) {
      short8 a[4], b[4];
      #pragma unroll
      for (int m = 0; m < 4; ++m) {
        int row = wr * 64 + m * 16 + (lane & 15);
        int ch = (kk * 4 + (lane >> 4)) ^ (row & 7);
        a[m] = *reinterpret_cast<const short8*>(&As[cur][row * 64 + ch * 8]);
      }
      #pragma unroll
      for (int n = 0; n < 4; ++n) {
        int row = wc * 64 + n * 16 + (lane & 15);
        int ch = (kk * 4 + (lane >> 4)) ^ (row & 7);
        b[n] = *reinterpret_cast<const short8*>(&Bs[cur][row * 64 + ch * 8]);
      }
      #pragma unroll
      for (int m = 0; m < 4; ++m)
        #pragma unroll
        for (int n = 0; n < 4; ++n)
          acc[m][n] = __builtin_amdgcn_mfma_f32_16x16x32_bf16(a[m], b[n], acc[m][n], 0, 0, 0);
    }
    __syncthreads();
    cur ^= 1;
  }

  float* dst = pg + (size_t)bz * 512 * 6144;
  #pragma unroll
  for (int m = 0; m < 4; ++m)
    #pragma unroll
    for (int n = 0; n < 4; ++n)
      #pragma unroll
      for (int j = 0; j < 4; ++j) {
        int row = m0 + wr * 64 + m * 16 + (lane >> 4) * 4 + j;
        int col = n0 + wc * 64 + n * 16 + (lane & 15);
        dst[(size_t)row * 6144 + col] = acc[m][n][j];
      }
}

// ---------------------------------------------------------------------------
// Kernel D: combine splits for q cols (-> qb) and k cols (-> Kb rows P..L).
// ---------------------------------------------------------------------------
__global__ __launch_bounds__(256) void combine_qk(
    const float* __restrict__ pg, ushort* __restrict__ qb,
    ushort* __restrict__ Kb)
{
  int id = blockIdx.x * 256 + threadIdx.x;
  int m = id / 640;
  int c8 = (id - m * 640) * 8;
  const float* p0 = pg + (size_t)m * 6144 + c8;
  const float* p1 = p0 + (size_t)512 * 6144;
  short8 s;
  #pragma unroll
  for (int e = 0; e < 8; ++e) s[e] = f2bf(p0[e] + p1[e]);
  if (c8 < 4096) {
    *reinterpret_cast<short8*>(&qb[(size_t)m * 4096 + c8]) = s;
  } else {
    int o = c8 - 4096;
    int hk = o >> 7, d0 = o & 127;
    int l = P_ + m;
    int ch = (d0 >> 3) ^ (l & 7);
    #pragma unroll
    for (int g = 0; g < 4; ++g)
      *reinterpret_cast<short8*>(&Kb[((size_t)(hk * 4 + g) * L_ + l) * 128 + ch * 8]) = s;
  }
}

// ---------------------------------------------------------------------------
// Kernel E: combine splits for v cols -> Vtb (transposed) rows P..L.
// ---------------------------------------------------------------------------
__global__ __launch_bounds__(256) void combine_v(
    const float* __restrict__ pg, ushort* __restrict__ Vtb)
{
  int bz = blockIdx.x;
  int mt = bz & 7, hk = (bz >> 3) & 7, dh = bz >> 6;
  int m0 = mt * 64, d0 = dh * 64;
  int colbase = 5120 + hk * 128 + d0;
  __shared__ float T[64][65];
  int tid = threadIdx.x;
  int r = tid >> 2, q4 = tid & 3;

  #pragma unroll
  for (int i = 0; i < 4; ++i) {
    int c = (q4 * 4 + i) * 4;
    const float* p0 = pg + (size_t)(m0 + r) * 6144 + colbase + c;
    const float* p1 = p0 + (size_t)512 * 6144;
    float4 a = *reinterpret_cast<const float4*>(p0);
    float4 b = *reinterpret_cast<const float4*>(p1);
    T[r][c + 0] = a.x + b.x; T[r][c + 1] = a.y + b.y;
    T[r][c + 2] = a.z + b.z; T[r][c + 3] = a.w + b.w;
  }
  __syncthreads();

  #pragma unroll
  for (int p = 0; p < 2; ++p) {
    int idx = p * 256 + tid;
    int dloc = idx >> 3, cc = idx & 7;
    short8 s;
    #pragma unroll
    for (int e = 0; e < 8; ++e) s[e] = f2bf(T[cc * 8 + e][dloc]);
    int d = d0 + dloc;
    int pc = (cc & 4) | ((cc ^ (d >> 1)) & 3);
    int l0 = P_ + m0;
    #pragma unroll
    for (int g = 0; g < 4; ++g) {
      int h = hk * 4 + g;
      *reinterpret_cast<short8*>(&Vtb[((size_t)h * 128 + d) * (size_t)L_ + l0 + pc * 8]) = s;
    }
  }
}

// ---------------------------------------------------------------------------
// Kernel F: cache_K rows [0,P) -> Kb bf16, chunk-swizzled.
// ---------------------------------------------------------------------------
__global__ __launch_bounds__(256) void kconv(
    const float* __restrict__ cacheK, ushort* __restrict__ Kb)
{
  int h = blockIdx.x, lt = blockIdx.y;
  int tid = threadIdx.x;
  int r = tid >> 4, c = tid & 15;
  int l = lt * 16 + r;
  const float* src = &cacheK[((size_t)h * L_ + l) * 128 + c * 8];
  float4 f0 = *reinterpret_cast<const float4*>(src);
  float4 f1 = *reinterpret_cast<const float4*>(src + 4);
  short8 s;
  s[0] = f2bf(f0.x); s[1] = f2bf(f0.y); s[2] = f2bf(f0.z); s[3] = f2bf(f0.w);
  s[4] = f2bf(f1.x); s[5] = f2bf(f1.y); s[6] = f2bf(f1.z); s[7] = f2bf(f1.w);
  int pc = c ^ (l & 7);
  *reinterpret_cast<short8*>(&Kb[((size_t)h * L_ + l) * 128 + pc * 8]) = s;
}

// ---------------------------------------------------------------------------
// Kernel G: cache_V rows [0,P) -> Vtb bf16 transposed, pre-swizzled.
// ---------------------------------------------------------------------------
__global__ __launch_bounds__(256) void vconv(
    const float* __restrict__ cacheV, ushort* __restrict__ Vtb)
{
  int h = blockIdx.x, lt = blockIdx.y, dh = blockIdx.z;
  int l0 = lt * 64, d0 = dh * 64;
  __shared__ float T[64][65];
  int tid = threadIdx.x;
  int r4 = tid >> 4, c = tid & 15;

  #pragma unroll
  for (int p = 0; p < 4; ++p) {
    int r = p * 16 + r4;
    float4 f = *reinterpret_cast<const float4*>(
        &cacheV[((size_t)h * L_ + l0 + r) * 128 + d0 + c * 4]);
    T[r][c * 4 + 0] = f.x; T[r][c * 4 + 1] = f.y;
    T[r][c * 4 + 2] = f.z; T[r][c * 4 + 3] = f.w;
  }
  __syncthreads();

  int dr = tid >> 2, part = tid & 3;
  int d = d0 + dr;
  #pragma unroll
  for (int q = 0; q < 2; ++q) {
    int cc = part * 2 + q;
    short8 s;
    #pragma unroll
    for (int e = 0; e < 8; ++e) s[e] = f2bf(T[cc * 8 + e][dr]);
    int pc = (cc & 4) | ((cc ^ (d >> 1)) & 3);
    *reinterpret_cast<short8*>(&Vtb[((size_t)h * 128 + d) * (size_t)L_ + l0 + pc * 8]) = s;
  }
}

// ---------------------------------------------------------------------------
// Kernel H: GQA attention. L-split x8 -> 1024 blocks.
// v7: 4-buffer LDS pipeline (depth-2 prefetch), counted vmcnt + raw s_barrier
// instead of __syncthreads' vmcnt(0) drain. LDS 72 KB -> still 2 blocks/CU.
// ---------------------------------------------------------------------------
#define ATTN_STAGE(buf, l0g) do {                                             \
    _Pragma("unroll")                                                         \
    for (int it_ = 0; it_ < 2; ++it_)                                         \
      gload_lds16(&Kb[kbase + (size_t)((l0g) + w * 8 + it_ * 4 + (lane >> 4)) * 128 + (lane & 15) * 8], \
                  &Ks[buf][(w * 8 + it_ * 4) * 128]);                         \
    _Pragma("unroll")                                                         \
    for (int it_ = 0; it_ < 2; ++it_)                                         \
      gload_lds16(&Vtb[vbase + (size_t)(w * 32 + it_ * 16 + (lane >> 2)) * (size_t)L_ + (l0g) + (lane & 3) * 8], \
                  &Vt[buf][(w * 32 + it_ * 16) * 32]);                        \
  } while (0)

// compute one 32-l tile from buffer bufc (compile-time constant per copy)
#define ATTN_TILE(bufc) do {                                                  \
    f32x4 sc[2][2];                                                           \
    _Pragma("unroll")                                                         \
    for (int mb = 0; mb < 2; ++mb)                                            \
      _Pragma("unroll")                                                       \
      for (int rg = 0; rg < 2; ++rg)                                          \
        sc[mb][rg] = (f32x4){0.f, 0.f, 0.f, 0.f};                             \
    __builtin_amdgcn_s_setprio(1);                                            \
    _Pragma("unroll")                                                         \
    for (int kk = 0; kk < 4; ++kk) {                                          \
      short8 a[2];                                                            \
      _Pragma("unroll")                                                       \
      for (int mb = 0; mb < 2; ++mb) {                                        \
        int row = mb * 16 + lo16;                                             \
        int ch = (kk * 4 + hi) ^ (row & 7);                                   \
        a[mb] = *reinterpret_cast<const short8*>(&Ks[bufc][row * 128 + ch * 8]); \
      }                                                                       \
      _Pragma("unroll")                                                       \
      for (int mb = 0; mb < 2; ++mb)                                          \
        _Pragma("unroll")                                                     \
        for (int rg = 0; rg < 2; ++rg)                                        \
          sc[mb][rg] = __builtin_amdgcn_mfma_f32_16x16x32_bf16(a[mb], qreg[rg][kk], sc[mb][rg], 0, 0, 0); \
    }                                                                         \
    __builtin_amdgcn_s_setprio(0);                                            \
    _Pragma("unroll")                                                         \
    for (int mb = 0; mb < 2; ++mb)                                            \
      _Pragma("unroll")                                                       \
      for (int rg = 0; rg < 2; ++rg) {                                        \
        float e0 = __expf(sc[mb][rg][0]);                                     \
        float e1 = __expf(sc[mb][rg][1]);                                     \
        float e2 = __expf(sc[mb][rg][2]);                                     \
        float e3 = __expf(sc[mb][rg][3]);                                     \
        rs[rg] += (e0 + e1) + (e2 + e3);                                      \
        ushort4 u; u.x = f2bf(e0); u.y = f2bf(e1); u.z = f2bf(e2); u.w = f2bf(e3); \
        int q = w * 32 + rg * 16 + lo16;                                      \
        int ch = mb * 2 + (hi >> 1);                                          \
        int slot = ch ^ ((q >> 1) & 3);                                       \
        *reinterpret_cast<ushort4*>(&PsT[q * 32 + slot * 8 + (hi & 1) * 4]) = u; \
      }                                                                       \
    __builtin_amdgcn_s_setprio(1);                                            \
    {                                                                         \
      short8 b8[8];                                                           \
      _Pragma("unroll")                                                       \
      for (int n = 0; n < 8; ++n) {                                           \
        int d = n * 16 + lo16;                                                \
        int ch = hi ^ ((d >> 1) & 3);                                         \
        b8[n] = *reinterpret_cast<const short8*>(&Vt[bufc][d * 32 + ch * 8]); \
      }                                                                       \
      _Pragma("unroll")                                                       \
      for (int rg = 0; rg < 2; ++rg) {                                        \
        int q = w * 32 + rg * 16 + lo16;                                      \
        int sl = hi ^ ((q >> 1) & 3);                                         \
        short8 a = *reinterpret_cast<const short8*>(&PsT[q * 32 + sl * 8]);   \
        _Pragma("unroll")                                                     \
        for (int n = 0; n < 8; ++n)                                           \
          o[rg][n] = __builtin_amdgcn_mfma_f32_16x16x32_bf16(a, b8[n], o[rg][n], 0, 0, 0); \
      }                                                                       \
    }                                                                         \
    __builtin_amdgcn_s_setprio(0);                                            \
  } while (0)

__global__ __launch_bounds__(256, 2) void gqa_attn7(
    const ushort* __restrict__ qb, const ushort* __restrict__ Kb,
    const ushort* __restrict__ Vtb,
    ushort* __restrict__ pob, float* __restrict__ prs)
{
  const int b = blockIdx.x;
  const int s = b & 7;            // L-split, pinned to XCD b&7
  const int j = b >> 3;           // 0..127
  const int qt = j & 3;           // q-tile
  const int h = j >> 2;           // head 0..31
  const int tid = threadIdx.x, lane = tid & 63, w = tid >> 6;
  const int lo16 = lane & 15, hi = lane >> 4;

  __shared__ ushort Ks[4][32 * 128];   // 32 KB
  __shared__ ushort Vt[4][128 * 32];   // 32 KB
  __shared__ ushort PsT[128 * 32];     // 8 KB  [q][l]

  short8 qreg[2][4];
  #pragma unroll
  for (int rg = 0; rg < 2; ++rg) {
    int qrow = qt * 128 + w * 32 + rg * 16 + lo16;
    #pragma unroll
    for (int kk = 0; kk < 4; ++kk)
      qreg[rg][kk] = *reinterpret_cast<const short8*>(
          &qb[(size_t)qrow * 4096 + h * 128 + (kk * 4 + hi) * 8]);
  }

  f32x4 o[2][8];
  #pragma unroll
  for (int rg = 0; rg < 2; ++rg)
    #pragma unroll
    for (int n = 0; n < 8; ++n)
      o[rg][n] = (f32x4){0.f, 0.f, 0.f, 0.f};
  float rs[2] = {0.f, 0.f};

  const size_t kbase = ((size_t)h * L_ + s * 512) * 128;
  const size_t vbase = (size_t)h * 128 * (size_t)L_ + s * 512;

  // prologue: stage tiles 0 and 1; wait tile 0 (leave tile 1 in flight)
  ATTN_STAGE(0, 0);
  ATTN_STAGE(1, 32);
  asm volatile("s_waitcnt vmcnt(4)" ::: "memory");
  __builtin_amdgcn_s_barrier();

  // main loop: issue tile t+2, compute tile t, wait tile t+1 (counted vmcnt),
  // barrier WITHOUT draining tile t+2's loads.
  #pragma unroll
  for (int t = 0; t < 14; ++t) {
    ATTN_STAGE((t + 2) & 3, (t + 2) * 32);
    ATTN_TILE(t & 3);
    asm volatile("s_waitcnt vmcnt(4)" ::: "memory");
    __builtin_amdgcn_s_barrier();
  }
  // t = 14: nothing left to stage; wait tile 15 fully
  ATTN_TILE(2);
  asm volatile("s_waitcnt vmcnt(0)" ::: "memory");
  __builtin_amdgcn_s_barrier();
  // t = 15
  ATTN_TILE(3);

  // rowsum: q-row total = sum over the 4 hi-groups holding that q
  float rsum[2];
  #pragma unroll
  for (int rg = 0; rg < 2; ++rg) {
    float v = rs[rg];
    v += __shfl_xor(v, 16, 64);
    v += __shfl_xor(v, 32, 64);
    rsum[rg] = v;
  }

  const size_t pbase = (size_t)(s * 32 + h) * 512;
  #pragma unroll
  for (int rg = 0; rg < 2; ++rg)
    #pragma unroll
    for (int n = 0; n < 8; ++n)
      #pragma unroll
      for (int j2 = 0; j2 < 4; ++j2) {
        int row = qt * 128 + w * 32 + rg * 16 + hi * 4 + j2;
        pob[(pbase + row) * 128 + n * 16 + lo16] = f2bf(o[rg][n][j2]);
      }
  if (hi == 0) {
    #pragma unroll
    for (int rg = 0; rg < 2; ++rg) {
      int row = qt * 128 + w * 32 + rg * 16 + lo16;
      prs[pbase + row] = rsum[rg];
    }
  }
}

// ---------------------------------------------------------------------------
// Kernel I: out = sum_s pob / sum_s prs   (pob bf16, 8 splits)
// ---------------------------------------------------------------------------
__global__ __launch_bounds__(256) void reduce_out(
    const ushort* __restrict__ pob, const float* __restrict__ prs,
    float* __restrict__ out)
{
  int id = blockIdx.x * 256 + threadIdx.x;
  int m = id >> 10, dq = id & 1023;
  int h = dq >> 5, d4 = dq & 31;
  float4 acc = {0.f, 0.f, 0.f, 0.f};
  float rsum = 0.f;
  #pragma unroll
  for (int s = 0; s < 8; ++s) {
    size_t base = (size_t)(s * 32 + h) * 512 + m;
    ushort4 v = *reinterpret_cast<const ushort4*>(&pob[base * 128 + d4 * 4]);
    acc.x += bf2f(v.x); acc.y += bf2f(v.y); acc.z += bf2f(v.z); acc.w += bf2f(v.w);
    rsum += prs[base];
  }
  float inv = 1.f / rsum;
  float4 r; r.x = acc.x * inv; r.y = acc.y * inv; r.z = acc.z * inv; r.w = acc.w * inv;
  *reinterpret_cast<float4*>(&out[(size_t)m * 4096 + dq * 4]) = r;
}

extern "C" void kernel_launch(void* const* d_in, const int* in_sizes, int n_in,
                              void* d_out, int out_size, void* d_ws, size_t ws_size,
                              hipStream_t stream) {
  const float* X  = (const float*)d_in[0];
  const float* Wq = (const float*)d_in[1];
  const float* Wk = (const float*)d_in[2];
  const float* Wv = (const float*)d_in[3];
  const float* cK = (const float*)d_in[4];
  const float* cV = (const float*)d_in[5];
  float* out = (float*)d_out;

  ushort* qb  = (ushort*)d_ws;                        // [512][4096] bf16
  ushort* Xs  = qb  + (size_t)M_ * N_;                // [512][4096] bf16 pre-swz
  ushort* Kb  = Xs  + (size_t)M_ * N_;                // [32][4096][128] bf16 pre-swz
  ushort* Vtb = Kb  + (size_t)H_ * L_ * D_;           // [32][128][4096] bf16 pre-swz
  float*  prs = (float*)(Vtb + (size_t)H_ * L_ * D_); // [8][32][512] f32
  ushort* Wt  = (ushort*)(prs + 8 * 32 * 512);        // [6144][4096] bf16 pre-swz
  float*  pg  = (float*)(Wt + (size_t)6144 * 4096);   // [2][512][6144] f32
  ushort* pob = Wt;    // [8][32][512][128] bf16, 33.5 MB — aliases Wt (dead
                       // after qkv_gemm3; attn writes it after combine_* read pg)

  xconv<<<1024, 256, 0, stream>>>(X, Xs);
  wtrans<<<dim3(64, 96), 256, 0, stream>>>(Wq, Wk, Wv, Wt);
  qkv_gemm3<<<dim3(48, 4, 2), 256, 0, stream>>>(Xs, Wt, pg);
  combine_qk<<<1280, 256, 0, stream>>>(pg, qb, Kb);
  combine_v<<<128, 256, 0, stream>>>(pg, Vtb);
  kconv<<<dim3(32, 224), 256, 0, stream>>>(cK, Kb);
  vconv<<<dim3(32, 56, 2), 256, 0, stream>>>(cV, Vtb);
  gqa_attn7<<<1024, 256, 0, stream>>>(qb, Kb, Vtb, pob, prs);
  reduce_out<<<2048, 256, 0, stream>>>(pob, prs, out);
}

// Round 2
// 170.477 us; speedup vs baseline: 1.0519x; 1.0519x over previous
//
#include <hip/hip_runtime.h>

typedef __attribute__((ext_vector_type(8))) short short8;
typedef __attribute__((ext_vector_type(4))) float f32x4;

#define M_   512
#define N_   4096
#define D_   128
#define P_   3584
#define NKV  1024
#define L_   4096
#define H_   32

__device__ __forceinline__ ushort f2bf(float f) {
  union { float f; unsigned u; } v; v.f = f;
  unsigned r = (v.u + 0x7fffu + ((v.u >> 16) & 1u)) >> 16;
  return (ushort)r;
}
__device__ __forceinline__ float bf2f(ushort u) {
  union { unsigned u; float f; } v; v.u = ((unsigned)u) << 16;
  return v.f;
}

__device__ __forceinline__ void gload_lds16(const void* g, void* l) {
  __builtin_amdgcn_global_load_lds(
      (const __attribute__((address_space(1))) void*)g,
      (__attribute__((address_space(3))) void*)l, 16, 0, 0);
}

// ---------------------------------------------------------------------------
// Kernel A: X fp32 -> bf16, pre-swizzled chunk layout.
// ---------------------------------------------------------------------------
__global__ __launch_bounds__(256) void xconv(const float* __restrict__ X,
                                             ushort* __restrict__ Xs)
{
  int g = blockIdx.x * 256 + threadIdx.x;
  int row = g >> 9;
  int cir = g & 511;
  int grp = cir >> 3, ch = cir & 7;
  const float* src = &X[(size_t)row * 4096 + cir * 8];
  float4 f0 = *reinterpret_cast<const float4*>(src);
  float4 f1 = *reinterpret_cast<const float4*>(src + 4);
  short8 s;
  s[0] = f2bf(f0.x); s[1] = f2bf(f0.y); s[2] = f2bf(f0.z); s[3] = f2bf(f0.w);
  s[4] = f2bf(f1.x); s[5] = f2bf(f1.y); s[6] = f2bf(f1.z); s[7] = f2bf(f1.w);
  int dcol = grp * 64 + ((ch ^ (row & 7)) * 8);
  *reinterpret_cast<short8*>(&Xs[(size_t)row * 4096 + dcol]) = s;
}

// ---------------------------------------------------------------------------
// Kernel B: transpose+convert W -> Wt[6144][4096] bf16, pre-swizzled.
// ---------------------------------------------------------------------------
__global__ __launch_bounds__(256) void wtrans(
    const float* __restrict__ Wq, const float* __restrict__ Wk,
    const float* __restrict__ Wv, ushort* __restrict__ Wt)
{
  int bx = blockIdx.x;
  int by = blockIdx.y;
  const float* W; int wcols, c0;
  if (by < 64)      { W = Wq; wcols = 4096; c0 = by * 64; }
  else if (by < 80) { W = Wk; wcols = 1024; c0 = (by - 64) * 64; }
  else              { W = Wv; wcols = 1024; c0 = (by - 80) * 64; }
  int orow0 = by * 64;
  int r0 = bx * 64;
  __shared__ float T[64][65];
  int tid = threadIdx.x;

  #pragma unroll
  for (int i = 0; i < 4; ++i) {
    int r = i * 16 + (tid >> 4);
    int c4 = tid & 15;
    float4 f = *reinterpret_cast<const float4*>(&W[(size_t)(r0 + r) * wcols + c0 + c4 * 4]);
    T[r][c4 * 4 + 0] = f.x; T[r][c4 * 4 + 1] = f.y;
    T[r][c4 * 4 + 2] = f.z; T[r][c4 * 4 + 3] = f.w;
  }
  __syncthreads();

  #pragma unroll
  for (int i = 0; i < 2; ++i) {
    int j = i * 256 + tid;
    int orr = j >> 3;
    int ch = j & 7;
    short8 s;
    #pragma unroll
    for (int e = 0; e < 8; ++e) s[e] = f2bf(T[ch * 8 + e][orr]);
    int orow = orow0 + orr;
    int dstch = ch ^ (orow & 7);
    *reinterpret_cast<short8*>(&Wt[(size_t)orow * 4096 + r0 + dstch * 8]) = s;
  }
}

// ---------------------------------------------------------------------------
// Kernel C: K-split GEMM. pg[split][512][6144] = Xs @ Wt^T over K-half.
// ---------------------------------------------------------------------------
#define GEMM_STAGE(buf, k0g) do {                                             \
    _Pragma("unroll")                                                         \
    for (int i_ = 0; i_ < 4; ++i_) {                                          \
      int blk_ = w * 4 + i_;                                                  \
      gload_lds16(Asrc + (size_t)(blk_ * 8 + (lane >> 3)) * 4096 + (k0g) + (lane & 7) * 8, \
                  &As[buf][blk_ * 512]);                                      \
    }                                                                         \
    _Pragma("unroll")                                                         \
    for (int i_ = 0; i_ < 4; ++i_) {                                          \
      int blk_ = w * 4 + i_;                                                  \
      gload_lds16(Bsrc + (size_t)(blk_ * 8 + (lane >> 3)) * 4096 + (k0g) + (lane & 7) * 8, \
                  &Bs[buf][blk_ * 512]);                                      \
    }                                                                         \
  } while (0)

__global__ __launch_bounds__(256, 2) void qkv_gemm3(
    const ushort* __restrict__ Xs, const ushort* __restrict__ Wt,
    float* __restrict__ pg)
{
  const int bx = blockIdx.x;
  const int by = blockIdx.y;
  const int bz = blockIdx.z;
  const int tid = threadIdx.x, lane = tid & 63, w = tid >> 6;
  const int wr = w >> 1, wc = w & 1;
  const int m0 = by * 128, n0 = bx * 128;
  const int kb0 = bz * 2048;

  __shared__ ushort As[2][128 * 64];
  __shared__ ushort Bs[2][128 * 64];

  f32x4 acc[4][4];
  #pragma unroll
  for (int m = 0; m < 4; ++m)
    #pragma unroll
    for (int n = 0; n < 4; ++n)
      acc[m][n] = (f32x4){0.f, 0.f, 0.f, 0.f};

  const ushort* Asrc = Xs + (size_t)m0 * 4096;
  const ushort* Bsrc = Wt + (size_t)n0 * 4096;

  GEMM_STAGE(0, kb0);
  __syncthreads();
  int cur = 0;

  for (int kt = 0; kt < 32; ++kt) {
    if (kt + 1 < 32) GEMM_STAGE(cur ^ 1, kb0 + (kt + 1) * 64);
    #pragma unroll
    for (int kk = 0; kk < 2; ++kk) {
      short8 a[4], b[4];
      #pragma unroll
      for (int m = 0; m < 4; ++m) {
        int row = wr * 64 + m * 16 + (lane & 15);
        int ch = (kk * 4 + (lane >> 4)) ^ (row & 7);
        a[m] = *reinterpret_cast<const short8*>(&As[cur][row * 64 + ch * 8]);
      }
      #pragma unroll
      for (int n = 0; n < 4; ++n) {
        int row = wc * 64 + n * 16 + (lane & 15);
        int ch = (kk * 4 + (lane >> 4)) ^ (row & 7);
        b[n] = *reinterpret_cast<const short8*>(&Bs[cur][row * 64 + ch * 8]);
      }
      #pragma unroll
      for (int m = 0; m < 4; ++m)
        #pragma unroll
        for (int n = 0; n < 4; ++n)
          acc[m][n] = __builtin_amdgcn_mfma_f32_16x16x32_bf16(a[m], b[n], acc[m][n], 0, 0, 0);
    }
    __syncthreads();
    cur ^= 1;
  }

  float* dst = pg + (size_t)bz * 512 * 6144;
  #pragma unroll
  for (int m = 0; m < 4; ++m)
    #pragma unroll
    for (int n = 0; n < 4; ++n)
      #pragma unroll
      for (int j = 0; j < 4; ++j) {
        int row = m0 + wr * 64 + m * 16 + (lane >> 4) * 4 + j;
        int col = n0 + wc * 64 + n * 16 + (lane & 15);
        dst[(size_t)row * 6144 + col] = acc[m][n][j];
      }
}

// ---------------------------------------------------------------------------
// Kernel D: combine splits for q cols (-> qb) and k cols (-> Kb rows P..L).
// ---------------------------------------------------------------------------
__global__ __launch_bounds__(256) void combine_qk(
    const float* __restrict__ pg, ushort* __restrict__ qb,
    ushort* __restrict__ Kb)
{
  int id = blockIdx.x * 256 + threadIdx.x;
  int m = id / 640;
  int c8 = (id - m * 640) * 8;
  const float* p0 = pg + (size_t)m * 6144 + c8;
  const float* p1 = p0 + (size_t)512 * 6144;
  short8 s;
  #pragma unroll
  for (int e = 0; e < 8; ++e) s[e] = f2bf(p0[e] + p1[e]);
  if (c8 < 4096) {
    *reinterpret_cast<short8*>(&qb[(size_t)m * 4096 + c8]) = s;
  } else {
    int o = c8 - 4096;
    int hk = o >> 7, d0 = o & 127;
    int l = P_ + m;
    int ch = (d0 >> 3) ^ (l & 7);
    #pragma unroll
    for (int g = 0; g < 4; ++g)
      *reinterpret_cast<short8*>(&Kb[((size_t)(hk * 4 + g) * L_ + l) * 128 + ch * 8]) = s;
  }
}

// ---------------------------------------------------------------------------
// Kernel E: combine splits for v cols -> Vtb (transposed) rows P..L.
// NOTE: chunk content is l-interleaved: chunk c of a 32-l half holds
// l = {c*4..c*4+3, 16+c*4..16+c*4+3} so PV's A-fragment needs no shuffle.
// ---------------------------------------------------------------------------
__global__ __launch_bounds__(256) void combine_v(
    const float* __restrict__ pg, ushort* __restrict__ Vtb)
{
  int bz = blockIdx.x;
  int mt = bz & 7, hk = (bz >> 3) & 7, dh = bz >> 6;
  int m0 = mt * 64, d0 = dh * 64;
  int colbase = 5120 + hk * 128 + d0;
  __shared__ float T[64][65];
  int tid = threadIdx.x;
  int r = tid >> 2, q4 = tid & 3;

  #pragma unroll
  for (int i = 0; i < 4; ++i) {
    int c = (q4 * 4 + i) * 4;
    const float* p0 = pg + (size_t)(m0 + r) * 6144 + colbase + c;
    const float* p1 = p0 + (size_t)512 * 6144;
    float4 a = *reinterpret_cast<const float4*>(p0);
    float4 b = *reinterpret_cast<const float4*>(p1);
    T[r][c + 0] = a.x + b.x; T[r][c + 1] = a.y + b.y;
    T[r][c + 2] = a.z + b.z; T[r][c + 3] = a.w + b.w;
  }
  __syncthreads();

  #pragma unroll
  for (int p = 0; p < 2; ++p) {
    int idx = p * 256 + tid;
    int dloc = idx >> 3, cc = idx & 7;
    int half = cc >> 2, c4 = (cc & 3) * 4;
    short8 s;
    #pragma unroll
    for (int e = 0; e < 8; ++e) {
      int lrow = half * 32 + c4 + (e < 4 ? e : 16 + (e - 4));
      s[e] = f2bf(T[lrow][dloc]);
    }
    int d = d0 + dloc;
    int pc = (cc & 4) | ((cc ^ (d >> 1)) & 3);
    int l0 = P_ + m0;
    #pragma unroll
    for (int g = 0; g < 4; ++g) {
      int h = hk * 4 + g;
      *reinterpret_cast<short8*>(&Vtb[((size_t)h * 128 + d) * (size_t)L_ + l0 + pc * 8]) = s;
    }
  }
}

// ---------------------------------------------------------------------------
// Kernel F: cache_K rows [0,P) -> Kb bf16, chunk-swizzled.
// ---------------------------------------------------------------------------
__global__ __launch_bounds__(256) void kconv(
    const float* __restrict__ cacheK, ushort* __restrict__ Kb)
{
  int h = blockIdx.x, lt = blockIdx.y;
  int tid = threadIdx.x;
  int r = tid >> 4, c = tid & 15;
  int l = lt * 16 + r;
  const float* src = &cacheK[((size_t)h * L_ + l) * 128 + c * 8];
  float4 f0 = *reinterpret_cast<const float4*>(src);
  float4 f1 = *reinterpret_cast<const float4*>(src + 4);
  short8 s;
  s[0] = f2bf(f0.x); s[1] = f2bf(f0.y); s[2] = f2bf(f0.z); s[3] = f2bf(f0.w);
  s[4] = f2bf(f1.x); s[5] = f2bf(f1.y); s[6] = f2bf(f1.z); s[7] = f2bf(f1.w);
  int pc = c ^ (l & 7);
  *reinterpret_cast<short8*>(&Kb[((size_t)h * L_ + l) * 128 + pc * 8]) = s;
}

// ---------------------------------------------------------------------------
// Kernel G: cache_V rows [0,P) -> Vtb bf16 transposed, pre-swizzled,
// with the same l-interleaved chunk content as combine_v.
// ---------------------------------------------------------------------------
__global__ __launch_bounds__(256) void vconv(
    const float* __restrict__ cacheV, ushort* __restrict__ Vtb)
{
  int h = blockIdx.x, lt = blockIdx.y, dh = blockIdx.z;
  int l0 = lt * 64, d0 = dh * 64;
  __shared__ float T[64][65];
  int tid = threadIdx.x;
  int r4 = tid >> 4, c = tid & 15;

  #pragma unroll
  for (int p = 0; p < 4; ++p) {
    int r = p * 16 + r4;
    float4 f = *reinterpret_cast<const float4*>(
        &cacheV[((size_t)h * L_ + l0 + r) * 128 + d0 + c * 4]);
    T[r][c * 4 + 0] = f.x; T[r][c * 4 + 1] = f.y;
    T[r][c * 4 + 2] = f.z; T[r][c * 4 + 3] = f.w;
  }
  __syncthreads();

  int dr = tid >> 2, part = tid & 3;
  int d = d0 + dr;
  #pragma unroll
  for (int q = 0; q < 2; ++q) {
    int cc = part * 2 + q;
    int half = cc >> 2, c4 = (cc & 3) * 4;
    short8 s;
    #pragma unroll
    for (int e = 0; e < 8; ++e) {
      int lrow = half * 32 + c4 + (e < 4 ? e : 16 + (e - 4));
      s[e] = f2bf(T[lrow][dr]);
    }
    int pc = (cc & 4) | ((cc ^ (d >> 1)) & 3);
    *reinterpret_cast<short8*>(&Vtb[((size_t)h * 128 + d) * (size_t)L_ + l0 + pc * 8]) = s;
  }
}

// ---------------------------------------------------------------------------
// Kernel H: GQA attention v8.
//  - 512 threads (8 waves x 16 q-rows), s-split 4 -> grid 512 = 2 blocks/CU,
//    ALL blocks co-resident (one round), 4 waves/SIMD.
//  - In-register P: QK output lanes feed PV A-fragment directly via the
//    k<->l permutation matched by Vtb's interleaved chunk content. No PsT.
//  - 4-buffer K/V LDS (64 KB), depth-2 prefetch, counted vmcnt(2).
// ---------------------------------------------------------------------------
#define ATTN_STAGE(buf, l0g) do {                                             \
    gload_lds16(&Kb[kbase + (size_t)((l0g) + w * 4 + (lane >> 4)) * 128 + (lane & 15) * 8], \
                &Ks[buf][(w * 4) * 128]);                                     \
    gload_lds16(&Vtb[vbase + (size_t)(w * 16 + (lane >> 2)) * (size_t)L_ + (l0g) + (lane & 3) * 8], \
                &Vt[buf][(w * 16) * 32]);                                     \
  } while (0)

#define ATTN_TILE(bufc) do {                                                  \
    const ushort* Ksb = &Ks[bufc][0];                                         \
    const ushort* Vsb = &Vt[bufc][0];                                         \
    f32x4 sc0 = (f32x4){0.f, 0.f, 0.f, 0.f};                                  \
    f32x4 sc1 = (f32x4){0.f, 0.f, 0.f, 0.f};                                  \
    __builtin_amdgcn_s_setprio(1);                                            \
    _Pragma("unroll")                                                         \
    for (int kk = 0; kk < 4; ++kk) {                                          \
      int ch = (kk * 4 + hi) ^ (lo16 & 7);                                    \
      short8 a0 = *reinterpret_cast<const short8*>(&Ksb[lo16 * 128 + ch * 8]); \
      short8 a1 = *reinterpret_cast<const short8*>(&Ksb[(16 + lo16) * 128 + ch * 8]); \
      sc0 = __builtin_amdgcn_mfma_f32_16x16x32_bf16(a0, qreg[kk], sc0, 0, 0, 0); \
      sc1 = __builtin_amdgcn_mfma_f32_16x16x32_bf16(a1, qreg[kk], sc1, 0, 0, 0); \
    }                                                                         \
    __builtin_amdgcn_s_setprio(0);                                            \
    short8 pa;                                                                \
    {                                                                         \
      float e0 = __expf(sc0[0]); float e1 = __expf(sc0[1]);                   \
      float e2 = __expf(sc0[2]); float e3 = __expf(sc0[3]);                   \
      float f0 = __expf(sc1[0]); float f1 = __expf(sc1[1]);                   \
      float f2 = __expf(sc1[2]); float f3 = __expf(sc1[3]);                   \
      rs += ((e0 + e1) + (e2 + e3)) + ((f0 + f1) + (f2 + f3));                \
      pa[0] = f2bf(e0); pa[1] = f2bf(e1); pa[2] = f2bf(e2); pa[3] = f2bf(e3); \
      pa[4] = f2bf(f0); pa[5] = f2bf(f1); pa[6] = f2bf(f2); pa[7] = f2bf(f3); \
    }                                                                         \
    __builtin_amdgcn_s_setprio(1);                                            \
    _Pragma("unroll")                                                         \
    for (int n = 0; n < 8; ++n) {                                             \
      int d = n * 16 + lo16;                                                  \
      int chv = hi ^ ((d >> 1) & 3);                                          \
      short8 bn = *reinterpret_cast<const short8*>(&Vsb[d * 32 + chv * 8]);   \
      o[n] = __builtin_amdgcn_mfma_f32_16x16x32_bf16(pa, bn, o[n], 0, 0, 0);  \
    }                                                                         \
    __builtin_amdgcn_s_setprio(0);                                            \
  } while (0)

__global__ __launch_bounds__(512, 4) void gqa_attn8(
    const ushort* __restrict__ qb, const ushort* __restrict__ Kb,
    const ushort* __restrict__ Vtb,
    ushort* __restrict__ pob, float* __restrict__ prs)
{
  const int b = blockIdx.x;
  const int s = b & 3;            // L-split (1024 l each); XCD x serves s = x&3
  const int j = b >> 2;           // 0..127
  const int qt = j & 3;           // q-tile
  const int h = j >> 2;           // head 0..31
  const int tid = threadIdx.x, lane = tid & 63, w = tid >> 6;   // w: 0..7
  const int lo16 = lane & 15, hi = lane >> 4;

  __shared__ ushort Ks[4][32 * 128];   // 32 KB
  __shared__ ushort Vt[4][128 * 32];   // 32 KB

  short8 qreg[4];
  {
    int qrow = qt * 128 + w * 16 + lo16;
    #pragma unroll
    for (int kk = 0; kk < 4; ++kk)
      qreg[kk] = *reinterpret_cast<const short8*>(
          &qb[(size_t)qrow * 4096 + h * 128 + (kk * 4 + hi) * 8]);
  }

  f32x4 o[8];
  #pragma unroll
  for (int n = 0; n < 8; ++n)
    o[n] = (f32x4){0.f, 0.f, 0.f, 0.f};
  float rs = 0.f;

  const size_t kbase = ((size_t)h * L_ + s * 1024) * 128;
  const size_t vbase = (size_t)h * 128 * (size_t)L_ + s * 1024;

  // prologue: stage tiles 0 and 1; wait tile 0 (leave tile 1 in flight)
  ATTN_STAGE(0, 0);
  ATTN_STAGE(1, 32);
  asm volatile("s_waitcnt vmcnt(2)" ::: "memory");
  __builtin_amdgcn_s_barrier();

  // main loop over 32 l-tiles: issue t+2, compute t, wait t+1 (counted).
  for (int t = 0; t < 30; ++t) {
    ATTN_STAGE((t + 2) & 3, (t + 2) * 32);
    ATTN_TILE(t & 3);
    asm volatile("s_waitcnt vmcnt(2)" ::: "memory");
    __builtin_amdgcn_s_barrier();
  }
  ATTN_TILE(2);                               // tile 30
  asm volatile("s_waitcnt vmcnt(0)" ::: "memory");
  __builtin_amdgcn_s_barrier();
  ATTN_TILE(3);                               // tile 31

  // rowsum: q-row total = sum over the 4 hi-groups holding that q
  float rsum = rs;
  rsum += __shfl_xor(rsum, 16, 64);
  rsum += __shfl_xor(rsum, 32, 64);

  const size_t pbase = (size_t)(s * 32 + h) * 512;
  #pragma unroll
  for (int n = 0; n < 8; ++n)
    #pragma unroll
    for (int j2 = 0; j2 < 4; ++j2) {
      int row = qt * 128 + w * 16 + hi * 4 + j2;
      pob[(pbase + row) * 128 + n * 16 + lo16] = f2bf(o[n][j2]);
    }
  if (hi == 0) {
    int row = qt * 128 + w * 16 + lo16;
    prs[pbase + row] = rsum;
  }
}

// ---------------------------------------------------------------------------
// Kernel I: out = sum_s pob / sum_s prs   (pob bf16, 4 splits)
// ---------------------------------------------------------------------------
__global__ __launch_bounds__(256) void reduce_out(
    const ushort* __restrict__ pob, const float* __restrict__ prs,
    float* __restrict__ out)
{
  int id = blockIdx.x * 256 + threadIdx.x;
  int m = id >> 10, dq = id & 1023;
  int h = dq >> 5, d4 = dq & 31;
  float4 acc = {0.f, 0.f, 0.f, 0.f};
  float rsum = 0.f;
  #pragma unroll
  for (int s = 0; s < 4; ++s) {
    size_t base = (size_t)(s * 32 + h) * 512 + m;
    ushort4 v = *reinterpret_cast<const ushort4*>(&pob[base * 128 + d4 * 4]);
    acc.x += bf2f(v.x); acc.y += bf2f(v.y); acc.z += bf2f(v.z); acc.w += bf2f(v.w);
    rsum += prs[base];
  }
  float inv = 1.f / rsum;
  float4 r; r.x = acc.x * inv; r.y = acc.y * inv; r.z = acc.z * inv; r.w = acc.w * inv;
  *reinterpret_cast<float4*>(&out[(size_t)m * 4096 + dq * 4]) = r;
}

extern "C" void kernel_launch(void* const* d_in, const int* in_sizes, int n_in,
                              void* d_out, int out_size, void* d_ws, size_t ws_size,
                              hipStream_t stream) {
  const float* X  = (const float*)d_in[0];
  const float* Wq = (const float*)d_in[1];
  const float* Wk = (const float*)d_in[2];
  const float* Wv = (const float*)d_in[3];
  const float* cK = (const float*)d_in[4];
  const float* cV = (const float*)d_in[5];
  float* out = (float*)d_out;

  ushort* qb  = (ushort*)d_ws;                        // [512][4096] bf16
  ushort* Xs  = qb  + (size_t)M_ * N_;                // [512][4096] bf16 pre-swz
  ushort* Kb  = Xs  + (size_t)M_ * N_;                // [32][4096][128] bf16 pre-swz
  ushort* Vtb = Kb  + (size_t)H_ * L_ * D_;           // [32][128][4096] bf16 pre-swz
  float*  prs = (float*)(Vtb + (size_t)H_ * L_ * D_); // [4][32][512] f32
  ushort* Wt  = (ushort*)(prs + 8 * 32 * 512);        // [6144][4096] bf16 pre-swz
  float*  pg  = (float*)(Wt + (size_t)6144 * 4096);   // [2][512][6144] f32
  ushort* pob = Wt;    // [4][32][512][128] bf16, 16.8 MB — aliases Wt (dead
                       // after qkv_gemm3; attn writes it after combine_* read pg)

  xconv<<<1024, 256, 0, stream>>>(X, Xs);
  wtrans<<<dim3(64, 96), 256, 0, stream>>>(Wq, Wk, Wv, Wt);
  qkv_gemm3<<<dim3(48, 4, 2), 256, 0, stream>>>(Xs, Wt, pg);
  combine_qk<<<1280, 256, 0, stream>>>(pg, qb, Kb);
  combine_v<<<128, 256, 0, stream>>>(pg, Vtb);
  kconv<<<dim3(32, 224), 256, 0, stream>>>(cK, Kb);
  vconv<<<dim3(32, 56, 2), 256, 0, stream>>>(cV, Vtb);
  gqa_attn8<<<512, 512, 0, stream>>>(qb, Kb, Vtb, pob, prs);
  reduce_out<<<2048, 256, 0, stream>>>(pob, prs, out);
}